// Round 3
// baseline (534.764 us; speedup 1.0000x reference)
//
#include <hip/hip_runtime.h>
#include <hip/hip_bf16.h>
#include <math.h>

#define DIM   2048
#define NH    16
#define HD    128
#define SEQ   2048
#define BATCH 2
#define QKVN  6144   // 3*DIM

typedef __attribute__((ext_vector_type(8))) short short8;
typedef __attribute__((ext_vector_type(4))) float f32x4;
typedef __attribute__((ext_vector_type(4))) unsigned int u32x4;

static __device__ __forceinline__ unsigned short f2bf(float f) {
    __hip_bfloat16 h = __float2bfloat16(f);
    return *reinterpret_cast<unsigned short*>(&h);
}

// async global->LDS, 16B per lane; LDS dest = base + lane*16 (wave-uniform base)
static __device__ __forceinline__ void gload16(const __hip_bfloat16* g, __hip_bfloat16* l) {
    __builtin_amdgcn_global_load_lds(
        (__attribute__((address_space(1))) void*)(g),
        (__attribute__((address_space(3))) void*)(l), 16, 0, 0);
}

// ---------------- fused cast fp32 -> bf16 (x + 4 weights, one launch) ----------------
__global__ __launch_bounds__(256) void cast_all(const float* __restrict__ x,
                                                const float* __restrict__ wq,
                                                const float* __restrict__ wk,
                                                const float* __restrict__ wv,
                                                const float* __restrict__ wo,
                                                __hip_bfloat16* __restrict__ xb,
                                                __hip_bfloat16* __restrict__ wqkvb,
                                                __hip_bfloat16* __restrict__ wob) {
    const int VX = (BATCH * SEQ * DIM) / 4;   // 2097152 float4's
    const int VW = (DIM * DIM) / 4;           // 1048576
    int v = blockIdx.x * blockDim.x + threadIdx.x;
    const float* src; __hip_bfloat16* dst; int off;
    if (v < VX)               { src = x;  dst = xb;                            off = v; }
    else if (v < VX + VW)     { src = wq; dst = wqkvb;                         off = v - VX; }
    else if (v < VX + 2 * VW) { src = wk; dst = wqkvb + (size_t)DIM * DIM;     off = v - VX - VW; }
    else if (v < VX + 3 * VW) { src = wv; dst = wqkvb + 2ull * DIM * DIM;      off = v - VX - 2 * VW; }
    else                      { src = wo; dst = wob;                           off = v - VX - 3 * VW; }
    float4 f = *(const float4*)(src + (size_t)off * 4);
    union { unsigned short u[4]; uint2 d; } pk;
    pk.u[0] = f2bf(f.x); pk.u[1] = f2bf(f.y); pk.u[2] = f2bf(f.z); pk.u[3] = f2bf(f.w);
    *(uint2*)(dst + (size_t)off * 4) = pk.d;
}

// ---------------- RoPE (in-place, 4 pairs / thread, fast sincos) ----------------
__global__ __launch_bounds__(256) void rope_kernel(__hip_bfloat16* __restrict__ qkv) {
    int idx = blockIdx.x * blockDim.x + threadIdx.x;   // 4096*16*16
    int m    = idx >> 8;           // row in [0,4096)
    int rest = idx & 255;
    int h    = rest >> 4;          // head
    int g    = rest & 15;          // group of 4 pairs
    int s    = m & (SEQ - 1);      // position
    size_t base = (size_t)m * QKVN + h * HD + g * 8;
    u32x4 qv = *(const u32x4*)(qkv + base);
    u32x4 kv = *(const u32x4*)(qkv + base + DIM);
    __hip_bfloat16 qa[8], ka[8];
    *(u32x4*)qa = qv; *(u32x4*)ka = kv;
#pragma unroll
    for (int j = 0; j < 4; j++) {
        int i = g * 4 + j;
        float theta = __expf(-((float)(2 * i) * (1.0f / (float)HD)) * 9.210340371976184f);
        float sn, cs;
        __sincosf((float)s * theta, &sn, &cs);
        float q0 = __bfloat162float(qa[2 * j]), q1 = __bfloat162float(qa[2 * j + 1]);
        qa[2 * j]     = __float2bfloat16(q0 * cs - q1 * sn);
        qa[2 * j + 1] = __float2bfloat16(q1 * cs + q0 * sn);
        float k0 = __bfloat162float(ka[2 * j]), k1 = __bfloat162float(ka[2 * j + 1]);
        ka[2 * j]     = __float2bfloat16(k0 * cs - k1 * sn);
        ka[2 * j + 1] = __float2bfloat16(k1 * cs + k0 * sn);
    }
    *(u32x4*)(qkv + base) = *(const u32x4*)qa;
    *(u32x4*)(qkv + base + DIM) = *(const u32x4*)ka;
}

// ---------------- V transpose: qkv V section -> Vt[bh][d][s] ----------------
__global__ __launch_bounds__(256) void vtrans_kernel(const __hip_bfloat16* __restrict__ qkv,
                                                     __hip_bfloat16* __restrict__ vt) {
    __shared__ __align__(16) __hip_bfloat16 T[64 * 64];
    int tid = threadIdx.x;
    int s0 = blockIdx.x * 64;
    int d0 = blockIdx.y * 64;
    int b  = blockIdx.z;
#pragma unroll
    for (int i = 0; i < 2; i++) {
        int ch = tid + 256 * i;
        int r  = ch >> 3;          // s row 0..63
        int cc = ch & 7;           // d chunk
        u32x4 v = *(const u32x4*)(qkv + ((size_t)(b * SEQ + s0 + r)) * QKVN + 2 * DIM + d0 + cc * 8);
        __hip_bfloat16 tmp[8];
        *(u32x4*)tmp = v;
#pragma unroll
        for (int j = 0; j < 8; j++) {
            int dl = cc * 8 + j;
            int chunk = ((r >> 3) ^ (dl & 7) ^ (dl >> 3)) & 7;
            T[dl * 64 + chunk * 8 + (r & 7)] = tmp[j];
        }
    }
    __syncthreads();
#pragma unroll
    for (int i = 0; i < 2; i++) {
        int ch = tid + 256 * i;
        int dl = ch >> 3;          // d row 0..63
        int sc = ch & 7;           // s chunk
        int chunk = (sc ^ (dl & 7) ^ (dl >> 3)) & 7;
        u32x4 v = *(const u32x4*)(T + dl * 64 + chunk * 8);
        int d = d0 + dl;
        int h = d >> 7, dd = d & 127;
        *(u32x4*)(vt + ((size_t)((b * NH + h) * HD + dd)) * SEQ + s0 + sc * 8) = v;
    }
}

// ---------------- bf16 GEMM, C[m,n] = sum_k A[m,k]*B[n,k] ----------------
__device__ __forceinline__ void storeC(float* C, size_t idx, float v) { C[idx] = v; }
__device__ __forceinline__ void storeC(__hip_bfloat16* C, size_t idx, float v) { C[idx] = __float2bfloat16(v); }

template <typename OutT>
__global__ __launch_bounds__(256) void gemm_bt(const __hip_bfloat16* __restrict__ A,
                                               const __hip_bfloat16* __restrict__ B,
                                               OutT* __restrict__ C, int M, int N, int K) {
    constexpr int BK = 64;
    __shared__ __align__(16) __hip_bfloat16 As[128 * BK];
    __shared__ __align__(16) __hip_bfloat16 Bs[128 * BK];
    int tid  = threadIdx.x;
    int lane = tid & 63;
    int wave = tid >> 6;
    int quad = lane >> 4;
    int l15  = lane & 15;
    int wr   = wave >> 1, wc = wave & 1;
    int m0 = blockIdx.y * 128;
    int n0 = blockIdx.x * 128;
    f32x4 acc[4][4] = {};

    for (int k0 = 0; k0 < K; k0 += BK) {
        __syncthreads();
#pragma unroll
        for (int c = 0; c < 4; c++) {
            int br = (wave * 4 + c) * 8;
            int r  = br + (lane >> 3);
            int cc = (lane & 7) ^ (r & 7);
            gload16(A + (size_t)(m0 + r) * K + k0 + cc * 8, As + br * 64);
            gload16(B + (size_t)(n0 + r) * K + k0 + cc * 8, Bs + br * 64);
        }
        __syncthreads();
#pragma unroll
        for (int kk = 0; kk < BK; kk += 32) {
            short8 af[4], bf4[4];
#pragma unroll
            for (int t = 0; t < 4; t++) {
                int Ra = wr * 64 + t * 16 + l15;
                int pa = ((kk >> 3) + quad) ^ (Ra & 7);
                af[t] = *(const short8*)(As + Ra * 64 + pa * 8);
                int Rb = wc * 64 + t * 16 + l15;
                int pb = ((kk >> 3) + quad) ^ (Rb & 7);
                bf4[t] = *(const short8*)(Bs + Rb * 64 + pb * 8);
            }
#pragma unroll
            for (int mt = 0; mt < 4; mt++)
#pragma unroll
                for (int nt = 0; nt < 4; nt++)
                    acc[mt][nt] = __builtin_amdgcn_mfma_f32_16x16x32_bf16(af[mt], bf4[nt], acc[mt][nt], 0, 0, 0);
        }
    }
#pragma unroll
    for (int mt = 0; mt < 4; mt++)
#pragma unroll
        for (int nt = 0; nt < 4; nt++)
#pragma unroll
            for (int r = 0; r < 4; r++) {
                int row = m0 + wr * 64 + mt * 16 + quad * 4 + r;
                int col = n0 + wc * 64 + nt * 16 + l15;
                storeC(C, (size_t)row * N + col, acc[mt][nt][r]);
            }
}

// ---------------- flash attention (causal), q-tile 128/block, 32 q-rows/wave ----------------
// grid: (16 qtiles desc, B*NH). 512 blocks, 2 co-resident/CU.
__global__ __launch_bounds__(256) void flash_kernel(const __hip_bfloat16* __restrict__ qkv,
                                                    const __hip_bfloat16* __restrict__ vt,
                                                    __hip_bfloat16* __restrict__ attn) {
    __shared__ __align__(16) __hip_bfloat16 Ks[64 * 128];    // K-tile, chunk-swizzled
    __shared__ __align__(16) __hip_bfloat16 Vts[128 * 64];   // Vt-tile, chunk-swizzled
    constexpr int LDP = 80;                                  // stride 160B: quads hit distinct banks
    __shared__ __align__(16) __hip_bfloat16 Ps[4 * 32 * LDP];
    int tid  = threadIdx.x;
    int lane = tid & 63;
    int wave = tid >> 6;
    int quad = lane >> 4;
    int l15  = lane & 15;
    int qt = 15 - blockIdx.x;    // big tiles dispatch first
    int bh = blockIdx.y;
    int b  = bh >> 4;
    int h  = bh & 15;
    size_t row0 = (size_t)b * SEQ;
    const __hip_bfloat16* vbase = vt + (size_t)bh * HD * SEQ;
    const float scale = 0.08838834764831845f;   // 1/sqrt(128)

    // Q fragments: 2 m-tiles x 4 k-chunks (A-operand layout)
    short8 qf[2][4];
#pragma unroll
    for (int mt = 0; mt < 2; mt++) {
        int qrow = qt * 128 + wave * 32 + mt * 16 + l15;
        const __hip_bfloat16* qptr = qkv + (row0 + qrow) * (size_t)QKVN + h * HD + quad * 8;
#pragma unroll
        for (int c = 0; c < 4; c++) qf[mt][c] = *(const short8*)(qptr + c * 32);
    }
    f32x4 o[2][8] = {};
    float mprev[2][4], lsum[2][4];
#pragma unroll
    for (int mt = 0; mt < 2; mt++)
#pragma unroll
        for (int r = 0; r < 4; r++) { mprev[mt][r] = -INFINITY; lsum[mt][r] = 0.f; }

    int ktend = 2 * qt + 2;
    for (int kt = 0; kt < ktend; kt++) {
        __syncthreads();
        // stage K tile [64 keys][128 d]
#pragma unroll
        for (int c = 0; c < 4; c++) {
            int br = (wave * 4 + c) * 4;
            int r  = br + (lane >> 4);
            int cc = (lane & 15) ^ (r & 15);
            gload16(qkv + (row0 + kt * 64 + r) * (size_t)QKVN + DIM + h * HD + cc * 8,
                    Ks + br * 128);
        }
        // stage Vt tile [128 d][64 keys]
#pragma unroll
        for (int c = 0; c < 4; c++) {
            int br = (wave * 4 + c) * 8;
            int r  = br + (lane >> 3);
            int cc = (lane & 7) ^ (r & 7);
            gload16(vbase + (size_t)r * SEQ + kt * 64 + cc * 8, Vts + br * 64);
        }
        __syncthreads();

        // S = Q K^T : each kf fragment feeds both m-tiles
        f32x4 s[2][4];
#pragma unroll
        for (int nt = 0; nt < 4; nt++) {
            f32x4 a0 = {}, a1 = {};
            int R = nt * 16 + l15;
#pragma unroll
            for (int c = 0; c < 4; c++) {
                int phys = (c * 4 + quad) ^ (R & 15);
                short8 kf = *(const short8*)(Ks + R * 128 + phys * 8);
                a0 = __builtin_amdgcn_mfma_f32_16x16x32_bf16(qf[0][c], kf, a0, 0, 0, 0);
                a1 = __builtin_amdgcn_mfma_f32_16x16x32_bf16(qf[1][c], kf, a1, 0, 0, 0);
            }
            s[0][nt] = a0; s[1][nt] = a1;
        }
        bool diag = (kt >= 2 * qt);
#pragma unroll
        for (int mt = 0; mt < 2; mt++) {
#pragma unroll
            for (int nt = 0; nt < 4; nt++) {
                int key = kt * 64 + nt * 16 + l15;
#pragma unroll
                for (int r = 0; r < 4; r++) {
                    float v = s[mt][nt][r] * scale;
                    if (diag) {
                        int q = qt * 128 + wave * 32 + mt * 16 + quad * 4 + r;
                        if (key > q) v = -INFINITY;
                    }
                    s[mt][nt][r] = v;
                }
            }
            // online softmax for this m-tile
#pragma unroll
            for (int r = 0; r < 4; r++) {
                float v = fmaxf(fmaxf(s[mt][0][r], s[mt][1][r]), fmaxf(s[mt][2][r], s[mt][3][r]));
                v = fmaxf(v, __shfl_xor(v, 1));
                v = fmaxf(v, __shfl_xor(v, 2));
                v = fmaxf(v, __shfl_xor(v, 4));
                v = fmaxf(v, __shfl_xor(v, 8));
                float mnew = fmaxf(mprev[mt][r], v);
                float alpha = __expf(mprev[mt][r] - mnew);
                mprev[mt][r] = mnew;
                float sum = 0.f;
#pragma unroll
                for (int nt = 0; nt < 4; nt++) {
                    float p = __expf(s[mt][nt][r] - mnew);
                    s[mt][nt][r] = p;
                    sum += p;
                }
                sum += __shfl_xor(sum, 1);
                sum += __shfl_xor(sum, 2);
                sum += __shfl_xor(sum, 4);
                sum += __shfl_xor(sum, 8);
                lsum[mt][r] = lsum[mt][r] * alpha + sum;
#pragma unroll
                for (int dt = 0; dt < 8; dt++) o[mt][dt][r] *= alpha;
            }
        }
        // P (C-layout) -> LDS -> A-layout. Ps region is wave-private.
        __hip_bfloat16* pw = Ps + wave * 32 * LDP;
#pragma unroll
        for (int mt = 0; mt < 2; mt++)
#pragma unroll
            for (int nt = 0; nt < 4; nt++)
#pragma unroll
                for (int r = 0; r < 4; r++)
                    pw[(mt * 16 + quad * 4 + r) * LDP + nt * 16 + l15] = __float2bfloat16(s[mt][nt][r]);
        short8 pf[2][2];
#pragma unroll
        for (int mt = 0; mt < 2; mt++) {
            pf[mt][0] = *(const short8*)(pw + (mt * 16 + l15) * LDP + quad * 8);
            pf[mt][1] = *(const short8*)(pw + (mt * 16 + l15) * LDP + 32 + quad * 8);
        }
#pragma unroll
        for (int dt = 0; dt < 8; dt++) {
            int d = dt * 16 + l15;
            int p0 = (0 + quad) ^ (d & 7);
            int p1 = (4 + quad) ^ (d & 7);
            short8 vf0 = *(const short8*)(Vts + d * 64 + p0 * 8);
            short8 vf1 = *(const short8*)(Vts + d * 64 + p1 * 8);
#pragma unroll
            for (int mt = 0; mt < 2; mt++) {
                o[mt][dt] = __builtin_amdgcn_mfma_f32_16x16x32_bf16(pf[mt][0], vf0, o[mt][dt], 0, 0, 0);
                o[mt][dt] = __builtin_amdgcn_mfma_f32_16x16x32_bf16(pf[mt][1], vf1, o[mt][dt], 0, 0, 0);
            }
        }
    }
#pragma unroll
    for (int mt = 0; mt < 2; mt++) {
        int qbase = qt * 128 + wave * 32 + mt * 16 + quad * 4;
#pragma unroll
        for (int r = 0; r < 4; r++) {
            float inv = 1.0f / lsum[mt][r];
#pragma unroll
            for (int dt = 0; dt < 8; dt++) {
                attn[(row0 + qbase + r) * (size_t)DIM + h * HD + dt * 16 + l15] =
                    __float2bfloat16(o[mt][dt][r] * inv);
            }
        }
    }
}

extern "C" void kernel_launch(void* const* d_in, const int* in_sizes, int n_in,
                              void* d_out, int out_size, void* d_ws, size_t ws_size,
                              hipStream_t stream) {
    const float* x  = (const float*)d_in[0];
    const float* wq = (const float*)d_in[2];
    const float* wk = (const float*)d_in[3];
    const float* wv = (const float*)d_in[4];
    const float* wo = (const float*)d_in[5];
    float* out = (float*)d_out;

    char* ws = (char*)d_ws;
    __hip_bfloat16* xb    = (__hip_bfloat16*)(ws);                 // 4096x2048 (16MB)
    __hip_bfloat16* attn  = (__hip_bfloat16*)(ws);                 // reuses xb after QKV GEMM
    __hip_bfloat16* wqkvb = (__hip_bfloat16*)(ws + 16777216ull);   // 6144x2048 (24MB)
    __hip_bfloat16* wob   = (__hip_bfloat16*)(ws + 41943040ull);   // 2048x2048 (8MB)
    __hip_bfloat16* qkv   = (__hip_bfloat16*)(ws + 50331648ull);   // 4096x6144 (48MB)
    __hip_bfloat16* vtg   = (__hip_bfloat16*)(ws + 100663296ull);  // 32x128x2048 (16MB)

    const int nv = (BATCH * SEQ * DIM + 4 * DIM * DIM) / 4;   // 6291456 float4's
    cast_all<<<nv / 256, 256, 0, stream>>>(x, wq, wk, wv, wo, xb, wqkvb, wob);

    // QKV = xb @ wqkvb^T : M=4096, N=6144, K=2048
    gemm_bt<__hip_bfloat16><<<dim3(QKVN / 128, (BATCH * SEQ) / 128), 256, 0, stream>>>(
        xb, wqkvb, qkv, BATCH * SEQ, QKVN, DIM);

    rope_kernel<<<(BATCH * SEQ * NH * 16) / 256, 256, 0, stream>>>(qkv);

    vtrans_kernel<<<dim3(SEQ / 64, DIM / 64, BATCH), 256, 0, stream>>>(qkv, vtg);

    flash_kernel<<<dim3(16, BATCH * NH), 256, 0, stream>>>(qkv, vtg, attn);

    // out = attn @ wo^T : M=4096, N=2048, K=2048 (fp32 out)
    gemm_bt<float><<<dim3(DIM / 128, (BATCH * SEQ) / 128), 256, 0, stream>>>(
        attn, wob, out, BATCH * SEQ, DIM, DIM);
}

// Round 4
// 470.488 us; speedup vs baseline: 1.1366x; 1.1366x over previous
//
#include <hip/hip_runtime.h>
#include <hip/hip_bf16.h>
#include <math.h>

#define DIM   2048
#define NH    16
#define HD    128
#define SEQ   2048
#define BATCH 2
#define QKVN  6144   // 3*DIM

typedef __attribute__((ext_vector_type(8))) short short8;
typedef __attribute__((ext_vector_type(4))) float f32x4;
typedef __attribute__((ext_vector_type(4))) unsigned int u32x4;

static __device__ __forceinline__ unsigned short f2bf(float f) {
    __hip_bfloat16 h = __float2bfloat16(f);
    return *reinterpret_cast<unsigned short*>(&h);
}

// async global->LDS, 16B per lane; LDS dest = base + lane*16 (wave-uniform base)
static __device__ __forceinline__ void gload16(const __hip_bfloat16* g, __hip_bfloat16* l) {
    __builtin_amdgcn_global_load_lds(
        (__attribute__((address_space(1))) void*)(g),
        (__attribute__((address_space(3))) void*)(l), 16, 0, 0);
}

// ---------------- fused cast fp32 -> bf16 (x + 4 weights, one launch) ----------------
__global__ __launch_bounds__(256) void cast_all(const float* __restrict__ x,
                                                const float* __restrict__ wq,
                                                const float* __restrict__ wk,
                                                const float* __restrict__ wv,
                                                const float* __restrict__ wo,
                                                __hip_bfloat16* __restrict__ xb,
                                                __hip_bfloat16* __restrict__ wqkvb,
                                                __hip_bfloat16* __restrict__ wob) {
    const int VX = (BATCH * SEQ * DIM) / 4;
    const int VW = (DIM * DIM) / 4;
    int v = blockIdx.x * blockDim.x + threadIdx.x;
    const float* src; __hip_bfloat16* dst; int off;
    if (v < VX)               { src = x;  dst = xb;                            off = v; }
    else if (v < VX + VW)     { src = wq; dst = wqkvb;                         off = v - VX; }
    else if (v < VX + 2 * VW) { src = wk; dst = wqkvb + (size_t)DIM * DIM;     off = v - VX - VW; }
    else if (v < VX + 3 * VW) { src = wv; dst = wqkvb + 2ull * DIM * DIM;      off = v - VX - 2 * VW; }
    else                      { src = wo; dst = wob;                           off = v - VX - 3 * VW; }
    float4 f = *(const float4*)(src + (size_t)off * 4);
    union { unsigned short u[4]; uint2 d; } pk;
    pk.u[0] = f2bf(f.x); pk.u[1] = f2bf(f.y); pk.u[2] = f2bf(f.z); pk.u[3] = f2bf(f.w);
    *(uint2*)(dst + (size_t)off * 4) = pk.d;
}

// ---------------- RoPE (in-place, 4 pairs / thread, fast sincos) ----------------
__global__ __launch_bounds__(256) void rope_kernel(__hip_bfloat16* __restrict__ qkv) {
    int idx = blockIdx.x * blockDim.x + threadIdx.x;
    int m    = idx >> 8;
    int rest = idx & 255;
    int h    = rest >> 4;
    int g    = rest & 15;
    int s    = m & (SEQ - 1);
    size_t base = (size_t)m * QKVN + h * HD + g * 8;
    u32x4 qv = *(const u32x4*)(qkv + base);
    u32x4 kv = *(const u32x4*)(qkv + base + DIM);
    __hip_bfloat16 qa[8], ka[8];
    *(u32x4*)qa = qv; *(u32x4*)ka = kv;
#pragma unroll
    for (int j = 0; j < 4; j++) {
        int i = g * 4 + j;
        float theta = __expf(-((float)(2 * i) * (1.0f / (float)HD)) * 9.210340371976184f);
        float sn, cs;
        __sincosf((float)s * theta, &sn, &cs);
        float q0 = __bfloat162float(qa[2 * j]), q1 = __bfloat162float(qa[2 * j + 1]);
        qa[2 * j]     = __float2bfloat16(q0 * cs - q1 * sn);
        qa[2 * j + 1] = __float2bfloat16(q1 * cs + q0 * sn);
        float k0 = __bfloat162float(ka[2 * j]), k1 = __bfloat162float(ka[2 * j + 1]);
        ka[2 * j]     = __float2bfloat16(k0 * cs - k1 * sn);
        ka[2 * j + 1] = __float2bfloat16(k1 * cs + k0 * sn);
    }
    *(u32x4*)(qkv + base) = *(const u32x4*)qa;
    *(u32x4*)(qkv + base + DIM) = *(const u32x4*)ka;
}

// ---------------- V transpose: qkv V section -> Vt[bh][d][s] ----------------
__global__ __launch_bounds__(256) void vtrans_kernel(const __hip_bfloat16* __restrict__ qkv,
                                                     __hip_bfloat16* __restrict__ vt) {
    __shared__ __align__(16) __hip_bfloat16 T[64 * 64];
    int tid = threadIdx.x;
    int s0 = blockIdx.x * 64;
    int d0 = blockIdx.y * 64;
    int b  = blockIdx.z;
#pragma unroll
    for (int i = 0; i < 2; i++) {
        int ch = tid + 256 * i;
        int r  = ch >> 3;
        int cc = ch & 7;
        u32x4 v = *(const u32x4*)(qkv + ((size_t)(b * SEQ + s0 + r)) * QKVN + 2 * DIM + d0 + cc * 8);
        __hip_bfloat16 tmp[8];
        *(u32x4*)tmp = v;
#pragma unroll
        for (int j = 0; j < 8; j++) {
            int dl = cc * 8 + j;
            int chunk = ((r >> 3) ^ (dl & 7) ^ (dl >> 3)) & 7;
            T[dl * 64 + chunk * 8 + (r & 7)] = tmp[j];
        }
    }
    __syncthreads();
#pragma unroll
    for (int i = 0; i < 2; i++) {
        int ch = tid + 256 * i;
        int dl = ch >> 3;
        int sc = ch & 7;
        int chunk = (sc ^ (dl & 7) ^ (dl >> 3)) & 7;
        u32x4 v = *(const u32x4*)(T + dl * 64 + chunk * 8);
        int d = d0 + dl;
        int h = d >> 7, dd = d & 127;
        *(u32x4*)(vt + ((size_t)((b * NH + h) * HD + dd)) * SEQ + s0 + sc * 8) = v;
    }
}

// ---------------- bf16 GEMM, C[m,n] = sum_k A[m,k]*B[n,k] ----------------
__device__ __forceinline__ void storeC(float* C, size_t idx, float v) { C[idx] = v; }
__device__ __forceinline__ void storeC(__hip_bfloat16* C, size_t idx, float v) { C[idx] = __float2bfloat16(v); }

template <typename OutT>
__global__ __launch_bounds__(256) void gemm_bt(const __hip_bfloat16* __restrict__ A,
                                               const __hip_bfloat16* __restrict__ B,
                                               OutT* __restrict__ C, int M, int N, int K) {
    constexpr int BK = 64;
    __shared__ __align__(16) __hip_bfloat16 As[128 * BK];
    __shared__ __align__(16) __hip_bfloat16 Bs[128 * BK];
    int tid  = threadIdx.x;
    int lane = tid & 63;
    int wave = tid >> 6;
    int quad = lane >> 4;
    int l15  = lane & 15;
    int wr   = wave >> 1, wc = wave & 1;
    int m0 = blockIdx.y * 128;
    int n0 = blockIdx.x * 128;
    f32x4 acc[4][4] = {};

    for (int k0 = 0; k0 < K; k0 += BK) {
        __syncthreads();
#pragma unroll
        for (int c = 0; c < 4; c++) {
            int br = (wave * 4 + c) * 8;
            int r  = br + (lane >> 3);
            int cc = (lane & 7) ^ (r & 7);
            gload16(A + (size_t)(m0 + r) * K + k0 + cc * 8, As + br * 64);
            gload16(B + (size_t)(n0 + r) * K + k0 + cc * 8, Bs + br * 64);
        }
        __syncthreads();
#pragma unroll
        for (int kk = 0; kk < BK; kk += 32) {
            short8 af[4], bf4[4];
#pragma unroll
            for (int t = 0; t < 4; t++) {
                int Ra = wr * 64 + t * 16 + l15;
                int pa = ((kk >> 3) + quad) ^ (Ra & 7);
                af[t] = *(const short8*)(As + Ra * 64 + pa * 8);
                int Rb = wc * 64 + t * 16 + l15;
                int pb = ((kk >> 3) + quad) ^ (Rb & 7);
                bf4[t] = *(const short8*)(Bs + Rb * 64 + pb * 8);
            }
#pragma unroll
            for (int mt = 0; mt < 4; mt++)
#pragma unroll
                for (int nt = 0; nt < 4; nt++)
                    acc[mt][nt] = __builtin_amdgcn_mfma_f32_16x16x32_bf16(af[mt], bf4[nt], acc[mt][nt], 0, 0, 0);
        }
    }
#pragma unroll
    for (int mt = 0; mt < 4; mt++)
#pragma unroll
        for (int nt = 0; nt < 4; nt++)
#pragma unroll
            for (int r = 0; r < 4; r++) {
                int row = m0 + wr * 64 + mt * 16 + quad * 4 + r;
                int col = n0 + wc * 64 + nt * 16 + l15;
                storeC(C, (size_t)row * N + col, acc[mt][nt][r]);
            }
}

// ---------------- flash attention (causal) ----------------
// qtile=128, paired (i, 15-i): every block does exactly 34 kt-iters.
// grid (8, 32) = 256 blocks = 1/CU. Double-buffered K/V staging: prefetch for
// tile kt+1 is issued AFTER the barrier guarding tile kt, so the barrier's
// vmcnt drain only waits on a DMA issued one compute-phase earlier.
__global__ __launch_bounds__(256) void flash_kernel(const __hip_bfloat16* __restrict__ qkv,
                                                    const __hip_bfloat16* __restrict__ vt,
                                                    __hip_bfloat16* __restrict__ attn) {
    __shared__ __align__(16) __hip_bfloat16 Ks[2][64 * 128];   // 2x16KB, chunk-swizzled
    __shared__ __align__(16) __hip_bfloat16 Vts[2][128 * 64];  // 2x16KB, chunk-swizzled
    __shared__ __align__(16) __hip_bfloat16 Ps[4][32 * 64];    // 16KB, chunk-swizzled
    int tid  = threadIdx.x;
    int lane = tid & 63;
    int wave = tid >> 6;
    int quad = lane >> 4;
    int l15  = lane & 15;
    int pairi = blockIdx.x;      // 0..7
    int bh = blockIdx.y;
    int b  = bh >> 4;
    int h  = bh & 15;
    size_t row0 = (size_t)b * SEQ;
    const __hip_bfloat16* vbase = vt + (size_t)bh * HD * SEQ;
    const float scale = 0.08838834764831845f;   // 1/sqrt(128)

    for (int seg = 0; seg < 2; seg++) {
        int qt = seg ? (15 - pairi) : pairi;

        short8 qf[2][4];
#pragma unroll
        for (int mt = 0; mt < 2; mt++) {
            int qrow = qt * 128 + wave * 32 + mt * 16 + l15;
            const __hip_bfloat16* qptr = qkv + (row0 + qrow) * (size_t)QKVN + h * HD + quad * 8;
#pragma unroll
            for (int c = 0; c < 4; c++) qf[mt][c] = *(const short8*)(qptr + c * 32);
        }
        f32x4 o[2][8] = {};
        float mprev[2][4], lsum[2][4];
#pragma unroll
        for (int mt = 0; mt < 2; mt++)
#pragma unroll
            for (int r = 0; r < 4; r++) { mprev[mt][r] = -INFINITY; lsum[mt][r] = 0.f; }

        int ktend = 2 * qt + 2;

        // prefetch tile 0 into buf 0
        {
#pragma unroll
            for (int c = 0; c < 4; c++) {
                int br = (wave * 4 + c) * 4;
                int r  = br + (lane >> 4);
                int cc = (lane & 15) ^ (r & 15);
                gload16(qkv + (row0 + r) * (size_t)QKVN + DIM + h * HD + cc * 8, &Ks[0][br * 128]);
            }
#pragma unroll
            for (int c = 0; c < 4; c++) {
                int br = (wave * 4 + c) * 8;
                int r  = br + (lane >> 3);
                int cc = (lane & 7) ^ (r & 7);
                gload16(vbase + (size_t)r * SEQ + cc * 8, &Vts[0][br * 64]);
            }
        }

        for (int kt = 0; kt < ktend; kt++) {
            __syncthreads();   // drains prefetch(kt); all waves done reading other buf
            if (kt + 1 < ktend) {
                int nb = (kt + 1) & 1;
                int koff = (kt + 1) * 64;
#pragma unroll
                for (int c = 0; c < 4; c++) {
                    int br = (wave * 4 + c) * 4;
                    int r  = br + (lane >> 4);
                    int cc = (lane & 15) ^ (r & 15);
                    gload16(qkv + (row0 + koff + r) * (size_t)QKVN + DIM + h * HD + cc * 8,
                            &Ks[nb][br * 128]);
                }
#pragma unroll
                for (int c = 0; c < 4; c++) {
                    int br = (wave * 4 + c) * 8;
                    int r  = br + (lane >> 3);
                    int cc = (lane & 7) ^ (r & 7);
                    gload16(vbase + (size_t)r * SEQ + koff + cc * 8, &Vts[nb][br * 64]);
                }
            }
            const __hip_bfloat16* ks  = Ks[kt & 1];
            const __hip_bfloat16* vts = Vts[kt & 1];

            // S = Q K^T : each kf fragment feeds both m-tiles
            f32x4 s[2][4];
#pragma unroll
            for (int nt = 0; nt < 4; nt++) {
                f32x4 a0 = {}, a1 = {};
                int R = nt * 16 + l15;
#pragma unroll
                for (int c = 0; c < 4; c++) {
                    int phys = (c * 4 + quad) ^ (R & 15);
                    short8 kf = *(const short8*)(ks + R * 128 + phys * 8);
                    a0 = __builtin_amdgcn_mfma_f32_16x16x32_bf16(qf[0][c], kf, a0, 0, 0, 0);
                    a1 = __builtin_amdgcn_mfma_f32_16x16x32_bf16(qf[1][c], kf, a1, 0, 0, 0);
                }
                s[0][nt] = a0; s[1][nt] = a1;
            }
            bool diag = (kt >= 2 * qt);
#pragma unroll
            for (int mt = 0; mt < 2; mt++) {
#pragma unroll
                for (int nt = 0; nt < 4; nt++) {
                    int key = kt * 64 + nt * 16 + l15;
#pragma unroll
                    for (int r = 0; r < 4; r++) {
                        float v = s[mt][nt][r] * scale;
                        if (diag) {
                            int q = qt * 128 + wave * 32 + mt * 16 + quad * 4 + r;
                            if (key > q) v = -INFINITY;
                        }
                        s[mt][nt][r] = v;
                    }
                }
#pragma unroll
                for (int r = 0; r < 4; r++) {
                    float v = fmaxf(fmaxf(s[mt][0][r], s[mt][1][r]), fmaxf(s[mt][2][r], s[mt][3][r]));
                    v = fmaxf(v, __shfl_xor(v, 1));
                    v = fmaxf(v, __shfl_xor(v, 2));
                    v = fmaxf(v, __shfl_xor(v, 4));
                    v = fmaxf(v, __shfl_xor(v, 8));
                    float mnew = fmaxf(mprev[mt][r], v);
                    float alpha = __expf(mprev[mt][r] - mnew);
                    mprev[mt][r] = mnew;
                    float sum = 0.f;
#pragma unroll
                    for (int nt = 0; nt < 4; nt++) {
                        float p = __expf(s[mt][nt][r] - mnew);
                        s[mt][nt][r] = p;
                        sum += p;
                    }
                    sum += __shfl_xor(sum, 1);
                    sum += __shfl_xor(sum, 2);
                    sum += __shfl_xor(sum, 4);
                    sum += __shfl_xor(sum, 8);
                    lsum[mt][r] = lsum[mt][r] * alpha + sum;
#pragma unroll
                    for (int dt = 0; dt < 8; dt++) o[mt][dt][r] *= alpha;
                }
            }
            // P (C-layout) -> LDS -> A-layout. Ps region is wave-private; XOR-swizzled.
            __hip_bfloat16* pw = Ps[wave];
#pragma unroll
            for (int mt = 0; mt < 2; mt++)
#pragma unroll
                for (int nt = 0; nt < 4; nt++)
#pragma unroll
                    for (int r = 0; r < 4; r++) {
                        int row = mt * 16 + quad * 4 + r;
                        int chunk = (nt * 2 + (l15 >> 3)) ^ (row & 7);
                        pw[row * 64 + chunk * 8 + (l15 & 7)] = __float2bfloat16(s[mt][nt][r]);
                    }
            short8 pf[2][2];
#pragma unroll
            for (int mt = 0; mt < 2; mt++) {
                int R = mt * 16 + l15;
                pf[mt][0] = *(const short8*)(pw + R * 64 + ((quad ^ (R & 7))) * 8);
                pf[mt][1] = *(const short8*)(pw + R * 64 + (((4 + quad) ^ (R & 7))) * 8);
            }
#pragma unroll
            for (int dt = 0; dt < 8; dt++) {
                int d = dt * 16 + l15;
                int p0 = (0 + quad) ^ (d & 7);
                int p1 = (4 + quad) ^ (d & 7);
                short8 vf0 = *(const short8*)(vts + d * 64 + p0 * 8);
                short8 vf1 = *(const short8*)(vts + d * 64 + p1 * 8);
#pragma unroll
                for (int mt = 0; mt < 2; mt++) {
                    o[mt][dt] = __builtin_amdgcn_mfma_f32_16x16x32_bf16(pf[mt][0], vf0, o[mt][dt], 0, 0, 0);
                    o[mt][dt] = __builtin_amdgcn_mfma_f32_16x16x32_bf16(pf[mt][1], vf1, o[mt][dt], 0, 0, 0);
                }
            }
        }
#pragma unroll
        for (int mt = 0; mt < 2; mt++) {
            int qbase = qt * 128 + wave * 32 + mt * 16 + quad * 4;
#pragma unroll
            for (int r = 0; r < 4; r++) {
                float inv = 1.0f / lsum[mt][r];
#pragma unroll
                for (int dt = 0; dt < 8; dt++) {
                    attn[(row0 + qbase + r) * (size_t)DIM + h * HD + dt * 16 + l15] =
                        __float2bfloat16(o[mt][dt][r] * inv);
                }
            }
        }
    }
}

extern "C" void kernel_launch(void* const* d_in, const int* in_sizes, int n_in,
                              void* d_out, int out_size, void* d_ws, size_t ws_size,
                              hipStream_t stream) {
    const float* x  = (const float*)d_in[0];
    const float* wq = (const float*)d_in[2];
    const float* wk = (const float*)d_in[3];
    const float* wv = (const float*)d_in[4];
    const float* wo = (const float*)d_in[5];
    float* out = (float*)d_out;

    char* ws = (char*)d_ws;
    __hip_bfloat16* xb    = (__hip_bfloat16*)(ws);                 // 4096x2048 (16MB)
    __hip_bfloat16* attn  = (__hip_bfloat16*)(ws);                 // reuses xb after QKV GEMM
    __hip_bfloat16* wqkvb = (__hip_bfloat16*)(ws + 16777216ull);   // 6144x2048 (24MB)
    __hip_bfloat16* wob   = (__hip_bfloat16*)(ws + 41943040ull);   // 2048x2048 (8MB)
    __hip_bfloat16* qkv   = (__hip_bfloat16*)(ws + 50331648ull);   // 4096x6144 (48MB)
    __hip_bfloat16* vtg   = (__hip_bfloat16*)(ws + 100663296ull);  // 32x128x2048 (16MB)

    const int nv = (BATCH * SEQ * DIM + 4 * DIM * DIM) / 4;
    cast_all<<<nv / 256, 256, 0, stream>>>(x, wq, wk, wv, wo, xb, wqkvb, wob);

    // QKV = xb @ wqkvb^T : M=4096, N=6144, K=2048
    gemm_bt<__hip_bfloat16><<<dim3(QKVN / 128, (BATCH * SEQ) / 128), 256, 0, stream>>>(
        xb, wqkvb, qkv, BATCH * SEQ, QKVN, DIM);

    rope_kernel<<<(BATCH * SEQ * NH * 16) / 256, 256, 0, stream>>>(qkv);

    vtrans_kernel<<<dim3(SEQ / 64, DIM / 64, BATCH), 256, 0, stream>>>(qkv, vtg);

    flash_kernel<<<dim3(8, BATCH * NH), 256, 0, stream>>>(qkv, vtg, attn);

    // out = attn @ wo^T : M=4096, N=2048, K=2048 (fp32 out)
    gemm_bt<float><<<dim3(DIM / 128, (BATCH * SEQ) / 128), 256, 0, stream>>>(
        attn, wob, out, BATCH * SEQ, DIM, DIM);
}

// Round 5
// 405.633 us; speedup vs baseline: 1.3183x; 1.1599x over previous
//
#include <hip/hip_runtime.h>
#include <hip/hip_bf16.h>
#include <math.h>

#define DIM   2048
#define NH    16
#define HD    128
#define SEQ   2048
#define BATCH 2
#define QKVN  6144   // 3*DIM

typedef __attribute__((ext_vector_type(8))) short short8;
typedef __attribute__((ext_vector_type(4))) float f32x4;
typedef __attribute__((ext_vector_type(4))) unsigned int u32x4;
typedef __attribute__((ext_vector_type(4))) _Float16 half4;

static __device__ __forceinline__ unsigned short f2bf(float f) {
    __hip_bfloat16 h = __float2bfloat16(f);
    return *reinterpret_cast<unsigned short*>(&h);
}

// async global->LDS, 16B per lane; LDS dest = base + lane*16 (wave-uniform base)
static __device__ __forceinline__ void gload16(const void* g, void* l) {
    __builtin_amdgcn_global_load_lds(
        (const __attribute__((address_space(1))) void*)(g),
        (__attribute__((address_space(3))) void*)(l), 16, 0, 0);
}

// ---------------- fused cast fp32 -> bf16 (x + 4 weights, one launch) ----------------
__global__ __launch_bounds__(256) void cast_all(const float* __restrict__ x,
                                                const float* __restrict__ wq,
                                                const float* __restrict__ wk,
                                                const float* __restrict__ wv,
                                                const float* __restrict__ wo,
                                                __hip_bfloat16* __restrict__ xb,
                                                __hip_bfloat16* __restrict__ wqkvb,
                                                __hip_bfloat16* __restrict__ wob) {
    const int VX = (BATCH * SEQ * DIM) / 4;
    const int VW = (DIM * DIM) / 4;
    int v = blockIdx.x * blockDim.x + threadIdx.x;
    const float* src; __hip_bfloat16* dst; int off;
    if (v < VX)               { src = x;  dst = xb;                            off = v; }
    else if (v < VX + VW)     { src = wq; dst = wqkvb;                         off = v - VX; }
    else if (v < VX + 2 * VW) { src = wk; dst = wqkvb + (size_t)DIM * DIM;     off = v - VX - VW; }
    else if (v < VX + 3 * VW) { src = wv; dst = wqkvb + 2ull * DIM * DIM;      off = v - VX - 2 * VW; }
    else                      { src = wo; dst = wob;                           off = v - VX - 3 * VW; }
    float4 f = *(const float4*)(src + (size_t)off * 4);
    union { unsigned short u[4]; uint2 d; } pk;
    pk.u[0] = f2bf(f.x); pk.u[1] = f2bf(f.y); pk.u[2] = f2bf(f.z); pk.u[3] = f2bf(f.w);
    *(uint2*)(dst + (size_t)off * 4) = pk.d;
}

// ---------------- RoPE (in-place, 4 pairs / thread, fast sincos) ----------------
__global__ __launch_bounds__(256) void rope_kernel(__hip_bfloat16* __restrict__ qkv) {
    int idx = blockIdx.x * blockDim.x + threadIdx.x;
    int m    = idx >> 8;
    int rest = idx & 255;
    int h    = rest >> 4;
    int g    = rest & 15;
    int s    = m & (SEQ - 1);
    size_t base = (size_t)m * QKVN + h * HD + g * 8;
    u32x4 qv = *(const u32x4*)(qkv + base);
    u32x4 kv = *(const u32x4*)(qkv + base + DIM);
    __hip_bfloat16 qa[8], ka[8];
    *(u32x4*)qa = qv; *(u32x4*)ka = kv;
#pragma unroll
    for (int j = 0; j < 4; j++) {
        int i = g * 4 + j;
        float theta = __expf(-((float)(2 * i) * (1.0f / (float)HD)) * 9.210340371976184f);
        float sn, cs;
        __sincosf((float)s * theta, &sn, &cs);
        float q0 = __bfloat162float(qa[2 * j]), q1 = __bfloat162float(qa[2 * j + 1]);
        qa[2 * j]     = __float2bfloat16(q0 * cs - q1 * sn);
        qa[2 * j + 1] = __float2bfloat16(q1 * cs + q0 * sn);
        float k0 = __bfloat162float(ka[2 * j]), k1 = __bfloat162float(ka[2 * j + 1]);
        ka[2 * j]     = __float2bfloat16(k0 * cs - k1 * sn);
        ka[2 * j + 1] = __float2bfloat16(k1 * cs + k0 * sn);
    }
    *(u32x4*)(qkv + base) = *(const u32x4*)qa;
    *(u32x4*)(qkv + base + DIM) = *(const u32x4*)ka;
}

// ---------------- V transpose: qkv V section (bf16) -> Vt[bh][d][s] (f16) ----------------
__global__ __launch_bounds__(256) void vtrans_kernel(const __hip_bfloat16* __restrict__ qkv,
                                                     _Float16* __restrict__ vt) {
    __shared__ __align__(16) _Float16 T[64 * 64];
    int tid = threadIdx.x;
    int s0 = blockIdx.x * 64;
    int d0 = blockIdx.y * 64;
    int b  = blockIdx.z;
#pragma unroll
    for (int i = 0; i < 2; i++) {
        int ch = tid + 256 * i;
        int r  = ch >> 3;
        int cc = ch & 7;
        u32x4 v = *(const u32x4*)(qkv + ((size_t)(b * SEQ + s0 + r)) * QKVN + 2 * DIM + d0 + cc * 8);
        __hip_bfloat16 tmp[8];
        *(u32x4*)tmp = v;
#pragma unroll
        for (int j = 0; j < 8; j++) {
            int dl = cc * 8 + j;
            int chunk = ((r >> 3) ^ (dl & 7) ^ (dl >> 3)) & 7;
            T[dl * 64 + chunk * 8 + (r & 7)] = (_Float16)__bfloat162float(tmp[j]);
        }
    }
    __syncthreads();
#pragma unroll
    for (int i = 0; i < 2; i++) {
        int ch = tid + 256 * i;
        int dl = ch >> 3;
        int sc = ch & 7;
        int chunk = (sc ^ (dl & 7) ^ (dl >> 3)) & 7;
        u32x4 v = *(const u32x4*)(T + dl * 64 + chunk * 8);
        int d = d0 + dl;
        int h = d >> 7, dd = d & 127;
        *(u32x4*)(vt + ((size_t)((b * NH + h) * HD + dd)) * SEQ + s0 + sc * 8) = v;
    }
}

// ---------------- bf16 GEMM, C[m,n] = sum_k A[m,k]*B[n,k] ----------------
__device__ __forceinline__ void storeC(float* C, size_t idx, float v) { C[idx] = v; }
__device__ __forceinline__ void storeC(__hip_bfloat16* C, size_t idx, float v) { C[idx] = __float2bfloat16(v); }

template <typename OutT>
__global__ __launch_bounds__(256) void gemm_bt(const __hip_bfloat16* __restrict__ A,
                                               const __hip_bfloat16* __restrict__ B,
                                               OutT* __restrict__ C, int M, int N, int K) {
    constexpr int BK = 64;
    __shared__ __align__(16) __hip_bfloat16 As[128 * BK];
    __shared__ __align__(16) __hip_bfloat16 Bs[128 * BK];
    int tid  = threadIdx.x;
    int lane = tid & 63;
    int wave = tid >> 6;
    int quad = lane >> 4;
    int l15  = lane & 15;
    int wr   = wave >> 1, wc = wave & 1;
    int m0 = blockIdx.y * 128;
    int n0 = blockIdx.x * 128;
    f32x4 acc[4][4] = {};

    for (int k0 = 0; k0 < K; k0 += BK) {
        __syncthreads();
#pragma unroll
        for (int c = 0; c < 4; c++) {
            int br = (wave * 4 + c) * 8;
            int r  = br + (lane >> 3);
            int cc = (lane & 7) ^ (r & 7);
            gload16(A + (size_t)(m0 + r) * K + k0 + cc * 8, As + br * 64);
            gload16(B + (size_t)(n0 + r) * K + k0 + cc * 8, Bs + br * 64);
        }
        __syncthreads();
#pragma unroll
        for (int kk = 0; kk < BK; kk += 32) {
            short8 af[4], bf4[4];
#pragma unroll
            for (int t = 0; t < 4; t++) {
                int Ra = wr * 64 + t * 16 + l15;
                int pa = ((kk >> 3) + quad) ^ (Ra & 7);
                af[t] = *(const short8*)(As + Ra * 64 + pa * 8);
                int Rb = wc * 64 + t * 16 + l15;
                int pb = ((kk >> 3) + quad) ^ (Rb & 7);
                bf4[t] = *(const short8*)(Bs + Rb * 64 + pb * 8);
            }
#pragma unroll
            for (int mt = 0; mt < 4; mt++)
#pragma unroll
                for (int nt = 0; nt < 4; nt++)
                    acc[mt][nt] = __builtin_amdgcn_mfma_f32_16x16x32_bf16(af[mt], bf4[nt], acc[mt][nt], 0, 0, 0);
        }
    }
#pragma unroll
    for (int mt = 0; mt < 4; mt++)
#pragma unroll
        for (int nt = 0; nt < 4; nt++)
#pragma unroll
            for (int r = 0; r < 4; r++) {
                int row = m0 + wr * 64 + mt * 16 + quad * 4 + r;
                int col = n0 + wc * 64 + nt * 16 + l15;
                storeC(C, (size_t)row * N + col, acc[mt][nt][r]);
            }
}

// ---------------- flash attention (causal) ----------------
// 512 threads = 8 waves = 2 groups x 4. qtile=128 (wave owns 32 q-rows).
// Group g processes half the key range; online-softmax partials merged in LDS.
// Pairs (i,15-i): every block 17+17 iters. grid (8,32)=256 blocks, 2 waves/SIMD.
// S^T = K·Q^T so P exits in B-operand layout for 16x16x16 f16 PV (no LDS round-trip).
__global__ __launch_bounds__(512, 2) void flash_kernel(const __hip_bfloat16* __restrict__ qkv,
                                                       const _Float16* __restrict__ vt,
                                                       __hip_bfloat16* __restrict__ attn) {
    __shared__ __align__(16) __hip_bfloat16 Ks[2][2][64 * 128];   // [group][buf] 64KB
    __shared__ __align__(16) _Float16 Vts[2][2][128 * 64];        // [group][buf] 64KB
    int tid  = threadIdx.x;
    int lane = tid & 63;
    int wave = tid >> 6;     // 0..7
    int grp  = wave >> 2;    // 0,1
    int wl   = wave & 3;     // wave-in-group
    int quad = lane >> 4;
    int l15  = lane & 15;
    int pairi = blockIdx.x;  // 0..7
    int bh = blockIdx.y;
    int b  = bh >> 4;
    int h  = bh & 15;
    size_t row0 = (size_t)b * SEQ;
    const _Float16* vbase = vt + (size_t)bh * HD * SEQ;
    const float scale = 0.08838834764831845f;   // 1/sqrt(128)
    const float NEG = -1e30f;

    auto stage = [&](int buf, int kt) {
#pragma unroll
        for (int c = 0; c < 4; c++) {
            int br = (wl * 4 + c) * 4;
            int r  = br + (lane >> 4);
            int cc = (lane & 15) ^ (r & 15);
            gload16(qkv + (row0 + kt * 64 + r) * (size_t)QKVN + DIM + h * HD + cc * 8,
                    &Ks[grp][buf][br * 128]);
        }
#pragma unroll
        for (int c = 0; c < 4; c++) {
            int br = (wl * 4 + c) * 8;
            int r  = br + (lane >> 3);
            int cc = (lane & 7) ^ ((r >> 1) & 7);   // phys c4 = c4 ^ (d&14)
            gload16(vbase + (size_t)r * SEQ + kt * 64 + cc * 8, &Vts[grp][buf][br * 64]);
        }
    };

    for (int seg = 0; seg < 2; seg++) {
        int qt = seg ? (15 - pairi) : pairi;
        int half = qt + 1;
        int kbase = grp ? half : 0;

        // Q fragments: [mt][c] = Q[q=l15][d=c*32+quad*8+j]  (A/B operand layout)
        short8 qf[2][4];
#pragma unroll
        for (int mt = 0; mt < 2; mt++) {
            int qrow = qt * 128 + wl * 32 + mt * 16 + l15;
            const __hip_bfloat16* qptr = qkv + (row0 + qrow) * (size_t)QKVN + h * HD + quad * 8;
#pragma unroll
            for (int c = 0; c < 4; c++) qf[mt][c] = *(const short8*)(qptr + c * 32);
        }
        f32x4 o[2][8] = {};
        float m_[2] = {NEG, NEG}, l_[2] = {0.f, 0.f};

        stage(0, kbase);   // prefetch first tile

        for (int i = 0; i < half; i++) {
            __syncthreads();   // drains own-group prefetch; other group in lockstep (same count)
            if (i + 1 < half) stage((i + 1) & 1, kbase + i + 1);
            int kt = kbase + i;
            const __hip_bfloat16* ks = Ks[grp][i & 1];
            const _Float16* vts = Vts[grp][i & 1];

            // S^T = K·Q^T : C-layout lane holds (q = l15, key = ktile*16+quad*4+r)
            f32x4 s[2][4] = {};
#pragma unroll
            for (int ktile = 0; ktile < 4; ktile++) {
                int R = ktile * 16 + l15;
#pragma unroll
                for (int c = 0; c < 4; c++) {
                    int phys = (c * 4 + quad) ^ (R & 15);
                    short8 kf = *(const short8*)(ks + R * 128 + phys * 8);
                    s[0][ktile] = __builtin_amdgcn_mfma_f32_16x16x32_bf16(kf, qf[0][c], s[0][ktile], 0, 0, 0);
                    s[1][ktile] = __builtin_amdgcn_mfma_f32_16x16x32_bf16(kf, qf[1][c], s[1][ktile], 0, 0, 0);
                }
            }
            bool diag = (kt >= 2 * qt);
            float alpha[2];
#pragma unroll
            for (int mt = 0; mt < 2; mt++) {
                int q = qt * 128 + wl * 32 + mt * 16 + l15;
#pragma unroll
                for (int ktile = 0; ktile < 4; ktile++)
#pragma unroll
                    for (int r = 0; r < 4; r++) {
                        float v = s[mt][ktile][r] * scale;
                        if (diag) {
                            int key = kt * 64 + ktile * 16 + quad * 4 + r;
                            if (key > q) v = NEG;
                        }
                        s[mt][ktile][r] = v;
                    }
                // row stats: in-lane over 16 vals, then across quads (xor16, xor32)
                float v = s[mt][0][0];
#pragma unroll
                for (int ktile = 0; ktile < 4; ktile++)
#pragma unroll
                    for (int r = 0; r < 4; r++) v = fmaxf(v, s[mt][ktile][r]);
                v = fmaxf(v, __shfl_xor(v, 16));
                v = fmaxf(v, __shfl_xor(v, 32));
                float mnew = fmaxf(m_[mt], v);
                alpha[mt] = __expf(m_[mt] - mnew);
                m_[mt] = mnew;
                float sum = 0.f;
#pragma unroll
                for (int ktile = 0; ktile < 4; ktile++)
#pragma unroll
                    for (int r = 0; r < 4; r++) {
                        float p = __expf(s[mt][ktile][r] - mnew);
                        s[mt][ktile][r] = p;
                        sum += p;
                    }
                sum += __shfl_xor(sum, 16);
                sum += __shfl_xor(sum, 32);
                l_[mt] = l_[mt] * alpha[mt] + sum;
#pragma unroll
                for (int dt = 0; dt < 8; dt++) o[mt][dt] *= alpha[mt];
            }
            // pack P to f16 B-operand: [n=q=l15][k=key=quad*4+j], j=r
            half4 pk[2][4];
#pragma unroll
            for (int mt = 0; mt < 2; mt++)
#pragma unroll
                for (int kc = 0; kc < 4; kc++)
#pragma unroll
                    for (int r = 0; r < 4; r++) pk[mt][kc][r] = (_Float16)s[mt][kc][r];
            // O^T += V^T·P : A = Vt[d][key] frags (b64, swizzled), B = pk (registers)
#pragma unroll
            for (int kc = 0; kc < 4; kc++)
#pragma unroll
                for (int dt = 0; dt < 8; dt++) {
                    int d = dt * 16 + l15;
                    int c4 = ((kc * 4 + quad) ^ (d & 14));
                    half4 vf = *(const half4*)(vts + d * 64 + c4 * 4);
                    o[0][dt] = __builtin_amdgcn_mfma_f32_16x16x16f16(vf, pk[0][kc], o[0][dt], 0, 0, 0);
                    o[1][dt] = __builtin_amdgcn_mfma_f32_16x16x16f16(vf, pk[1][kc], o[1][dt], 0, 0, 0);
                }
        }

        // ---- merge group partials + coalesced store ----
        __syncthreads();
        float* o1mb = (float*)&Ks[0][0][0];                    // 64KB mailbox
        float* mlmb = (float*)&Vts[0][0][0];                   // 4KB
        __hip_bfloat16* tb = (__hip_bfloat16*)((char*)&Vts[0][0][0] + 8192); // 32KB transpose
        if (grp == 1) {
            float* dst = o1mb + wl * 4096;
#pragma unroll
            for (int mt = 0; mt < 2; mt++)
#pragma unroll
                for (int dt = 0; dt < 8; dt++)
#pragma unroll
                    for (int r = 0; r < 4; r++)
                        dst[((mt * 8 + dt) * 4 + r) * 64 + lane] = o[mt][dt][r];
            float* ml = mlmb + (wl * 64 + lane) * 4;
            ml[0] = m_[0]; ml[1] = m_[1]; ml[2] = l_[0]; ml[3] = l_[1];
        }
        __syncthreads();
        if (grp == 0) {
            const float* src = o1mb + wl * 4096;
            const float* ml = mlmb + (wl * 64 + lane) * 4;
#pragma unroll
            for (int mt = 0; mt < 2; mt++) {
                float m1 = ml[mt], l1 = ml[2 + mt];
                float mm = fmaxf(m_[mt], m1);
                float a0 = __expf(m_[mt] - mm), a1 = __expf(m1 - mm);
                float linv = 1.0f / (l_[mt] * a0 + l1 * a1);
#pragma unroll
                for (int dt = 0; dt < 8; dt++)
#pragma unroll
                    for (int r = 0; r < 4; r++)
                        o[mt][dt][r] = (o[mt][dt][r] * a0 +
                                        src[((mt * 8 + dt) * 4 + r) * 64 + lane] * a1) * linv;
            }
            // transpose via wave-private LDS, then coalesced b128 stores
            __hip_bfloat16* tw = tb + wl * 4096;   // 32 rows x 128 d, swizzled c4 ^ ((q&7)<<2)
#pragma unroll
            for (int mt = 0; mt < 2; mt++)
#pragma unroll
                for (int dt = 0; dt < 8; dt++) {
                    int q32 = mt * 16 + l15;
                    int c4 = dt * 4 + quad;
                    int phys = c4 ^ ((q32 & 7) << 2);
                    union { unsigned short u[4]; uint2 dw; } pkb;
#pragma unroll
                    for (int r = 0; r < 4; r++) pkb.u[r] = f2bf(o[mt][dt][r]);
                    *(uint2*)(tw + q32 * 128 + phys * 4) = pkb.dw;
                }
#pragma unroll
            for (int pass = 0; pass < 8; pass++) {
                int q32 = pass * 4 + (lane >> 4);
                int p = l15;
                int phys = (p * 2) ^ ((q32 & 7) << 2);
                u32x4 val = *(const u32x4*)(tw + q32 * 128 + phys * 4);
                int qg = qt * 128 + wl * 32 + q32;
                *(u32x4*)(attn + (row0 + qg) * (size_t)DIM + h * HD + p * 8) = val;
            }
        }
        __syncthreads();   // protect mailbox/transpose space before next seg's prefetch
    }
}

extern "C" void kernel_launch(void* const* d_in, const int* in_sizes, int n_in,
                              void* d_out, int out_size, void* d_ws, size_t ws_size,
                              hipStream_t stream) {
    const float* x  = (const float*)d_in[0];
    const float* wq = (const float*)d_in[2];
    const float* wk = (const float*)d_in[3];
    const float* wv = (const float*)d_in[4];
    const float* wo = (const float*)d_in[5];
    float* out = (float*)d_out;

    char* ws = (char*)d_ws;
    __hip_bfloat16* xb    = (__hip_bfloat16*)(ws);                 // 4096x2048 (16MB)
    __hip_bfloat16* attn  = (__hip_bfloat16*)(ws);                 // reuses xb after QKV GEMM
    __hip_bfloat16* wqkvb = (__hip_bfloat16*)(ws + 16777216ull);   // 6144x2048 (24MB)
    __hip_bfloat16* wob   = (__hip_bfloat16*)(ws + 41943040ull);   // 2048x2048 (8MB)
    __hip_bfloat16* qkv   = (__hip_bfloat16*)(ws + 50331648ull);   // 4096x6144 (48MB)
    _Float16*       vtg   = (_Float16*)(ws + 100663296ull);        // 32x128x2048 f16 (16MB)

    const int nv = (BATCH * SEQ * DIM + 4 * DIM * DIM) / 4;
    cast_all<<<nv / 256, 256, 0, stream>>>(x, wq, wk, wv, wo, xb, wqkvb, wob);

    // QKV = xb @ wqkvb^T : M=4096, N=6144, K=2048
    gemm_bt<__hip_bfloat16><<<dim3(QKVN / 128, (BATCH * SEQ) / 128), 256, 0, stream>>>(
        xb, wqkvb, qkv, BATCH * SEQ, QKVN, DIM);

    rope_kernel<<<(BATCH * SEQ * NH * 16) / 256, 256, 0, stream>>>(qkv);

    vtrans_kernel<<<dim3(SEQ / 64, DIM / 64, BATCH), 256, 0, stream>>>(qkv, vtg);

    flash_kernel<<<dim3(8, BATCH * NH), 512, 0, stream>>>(qkv, vtg, attn);

    // out = attn @ wo^T : M=4096, N=2048, K=2048 (fp32 out)
    gemm_bt<float><<<dim3(DIM / 128, (BATCH * SEQ) / 128), 256, 0, stream>>>(
        attn, wob, out, BATCH * SEQ, DIM, DIM);
}

// Round 6
// 400.680 us; speedup vs baseline: 1.3346x; 1.0124x over previous
//
#include <hip/hip_runtime.h>
#include <hip/hip_bf16.h>
#include <math.h>

#define DIM   2048
#define NH    16
#define HD    128
#define SEQ   2048
#define BATCH 2
#define QKVN  6144   // 3*DIM

typedef __attribute__((ext_vector_type(8))) short short8;
typedef __attribute__((ext_vector_type(4))) float f32x4;
typedef __attribute__((ext_vector_type(4))) unsigned int u32x4;
typedef __attribute__((ext_vector_type(4))) _Float16 half4;

static __device__ __forceinline__ unsigned short f2bf(float f) {
    __hip_bfloat16 h = __float2bfloat16(f);
    return *reinterpret_cast<unsigned short*>(&h);
}

// async global->LDS, 16B per lane; LDS dest = base + lane*16 (wave-uniform base)
static __device__ __forceinline__ void gload16(const void* g, void* l) {
    __builtin_amdgcn_global_load_lds(
        (const __attribute__((address_space(1))) void*)(g),
        (__attribute__((address_space(3))) void*)(l), 16, 0, 0);
}

__device__ __forceinline__ void storeC_helper(float* C, size_t idx, float v) { C[idx] = v; }
__device__ __forceinline__ void storeC_helper(__hip_bfloat16* C, size_t idx, float v) { C[idx] = __float2bfloat16(v); }

// ---------------- fused cast fp32 -> bf16 (x + 4 weights, one launch) ----------------
__global__ __launch_bounds__(256) void cast_all(const float* __restrict__ x,
                                                const float* __restrict__ wq,
                                                const float* __restrict__ wk,
                                                const float* __restrict__ wv,
                                                const float* __restrict__ wo,
                                                __hip_bfloat16* __restrict__ xb,
                                                __hip_bfloat16* __restrict__ wqkvb,
                                                __hip_bfloat16* __restrict__ wob) {
    const int VX = (BATCH * SEQ * DIM) / 4;
    const int VW = (DIM * DIM) / 4;
    int v = blockIdx.x * blockDim.x + threadIdx.x;
    const float* src; __hip_bfloat16* dst; int off;
    if (v < VX)               { src = x;  dst = xb;                            off = v; }
    else if (v < VX + VW)     { src = wq; dst = wqkvb;                         off = v - VX; }
    else if (v < VX + 2 * VW) { src = wk; dst = wqkvb + (size_t)DIM * DIM;     off = v - VX - VW; }
    else if (v < VX + 3 * VW) { src = wv; dst = wqkvb + 2ull * DIM * DIM;      off = v - VX - 2 * VW; }
    else                      { src = wo; dst = wob;                           off = v - VX - 3 * VW; }
    float4 f = *(const float4*)(src + (size_t)off * 4);
    union { unsigned short u[4]; uint2 d; } pk;
    pk.u[0] = f2bf(f.x); pk.u[1] = f2bf(f.y); pk.u[2] = f2bf(f.z); pk.u[3] = f2bf(f.w);
    *(uint2*)(dst + (size_t)off * 4) = pk.d;
}

// ---------------- bf16 GEMM, C[m,n] = sum_k A[m,k]*B[n,k] ----------------
// MODE 0: plain store to C.  MODE 1: QKV-fused — n<4096: RoPE + bf16 store;
// n>=4096: V tile transposed via LDS, stored f16 to vt[bh][d][s].
template <int MODE, typename OutT>
__global__ __launch_bounds__(256) void gemm_bt(const __hip_bfloat16* __restrict__ A,
                                               const __hip_bfloat16* __restrict__ B,
                                               OutT* __restrict__ C,
                                               _Float16* __restrict__ vt,
                                               int M, int N, int K) {
    constexpr int BK = 64;
    __shared__ __align__(16) __hip_bfloat16 As[128 * BK];
    __shared__ __align__(16) __hip_bfloat16 Bs[128 * BK];
    int tid  = threadIdx.x;
    int lane = tid & 63;
    int wave = tid >> 6;
    int quad = lane >> 4;
    int l15  = lane & 15;
    int wr   = wave >> 1, wc = wave & 1;
    int m0 = blockIdx.y * 128;
    int n0 = blockIdx.x * 128;
    f32x4 acc[4][4] = {};

    for (int k0 = 0; k0 < K; k0 += BK) {
        __syncthreads();
#pragma unroll
        for (int c = 0; c < 4; c++) {
            int br = (wave * 4 + c) * 8;
            int r  = br + (lane >> 3);
            int cc = (lane & 7) ^ (r & 7);
            gload16(A + (size_t)(m0 + r) * K + k0 + cc * 8, As + br * 64);
            gload16(B + (size_t)(n0 + r) * K + k0 + cc * 8, Bs + br * 64);
        }
        __syncthreads();
#pragma unroll
        for (int kk = 0; kk < BK; kk += 32) {
            short8 af[4], bf4[4];
#pragma unroll
            for (int t = 0; t < 4; t++) {
                int Ra = wr * 64 + t * 16 + l15;
                int pa = ((kk >> 3) + quad) ^ (Ra & 7);
                af[t] = *(const short8*)(As + Ra * 64 + pa * 8);
                int Rb = wc * 64 + t * 16 + l15;
                int pb = ((kk >> 3) + quad) ^ (Rb & 7);
                bf4[t] = *(const short8*)(Bs + Rb * 64 + pb * 8);
            }
#pragma unroll
            for (int mt = 0; mt < 4; mt++)
#pragma unroll
                for (int nt = 0; nt < 4; nt++)
                    acc[mt][nt] = __builtin_amdgcn_mfma_f32_16x16x32_bf16(af[mt], bf4[nt], acc[mt][nt], 0, 0, 0);
        }
    }

    if (MODE == 1 && n0 >= 4096) {
        // ---- V branch: transpose 64x64 wave quadrant via LDS, store f16 ----
        __syncthreads();   // all waves done reading As/Bs
        _Float16* T = ((wave < 2) ? (_Float16*)As : (_Float16*)Bs) + (wave & 1) * 4096;
#pragma unroll
        for (int mt = 0; mt < 4; mt++)
#pragma unroll
            for (int nt = 0; nt < 4; nt++) {
                int dcol = nt * 16 + l15;
#pragma unroll
                for (int r = 0; r < 4; r++) {
                    int row = mt * 16 + quad * 4 + r;   // s within quadrant
                    int chunk = (row >> 3) ^ (dcol & 7);
                    T[dcol * 64 + chunk * 8 + (row & 7)] = (_Float16)acc[mt][nt][r];
                }
            }
        int h = (n0 - 4096) >> 7;
        int b = m0 >> 11;
        int sbase = (m0 & (SEQ - 1)) + wr * 64;
#pragma unroll
        for (int pass = 0; pass < 8; pass++) {
            int dl = pass * 8 + (lane >> 3);
            int sc = lane & 7;
            int chunk = sc ^ (dl & 7);
            u32x4 val = *(const u32x4*)(T + dl * 64 + chunk * 8);
            int d = wc * 64 + dl;
            *(u32x4*)(vt + ((size_t)((b * NH + h) * HD + d)) * SEQ + sbase + sc * 8) = val;
        }
        return;
    }

#pragma unroll
    for (int nt = 0; nt < 4; nt++) {
        int col = n0 + wc * 64 + nt * 16 + l15;
        float theta = 0.f;
        if (MODE == 1)
            theta = __expf(-((float)((col & 127) & ~1) * (1.0f / (float)HD)) * 9.210340371976184f);
#pragma unroll
        for (int mt = 0; mt < 4; mt++)
#pragma unroll
            for (int r = 0; r < 4; r++) {
                int row = m0 + wr * 64 + mt * 16 + quad * 4 + r;
                float val = acc[mt][nt][r];
                if (MODE == 1) {
                    float part = __shfl_xor(val, 1);
                    int s = row & (SEQ - 1);
                    float sn, cs;
                    __sincosf((float)s * theta, &sn, &cs);
                    val = (l15 & 1) ? val * cs + part * sn : val * cs - part * sn;
                }
                storeC_helper(C, (size_t)row * N + col, val);
            }
    }
}

// ---------------- flash attention (causal) ----------------
// 512 threads = 8 waves = 2 groups x 4. qtile=128 (wave owns 32 q-rows).
// Group g processes half the key range; online-softmax partials merged in LDS.
// Pairs (i,15-i): every block 17+17 iters. grid (8,32)=256 blocks, 2 waves/SIMD.
// S^T = K·Q^T so P exits in B-operand layout for 16x16x16 f16 PV.
__global__ __launch_bounds__(512, 2) void flash_kernel(const __hip_bfloat16* __restrict__ qkv,
                                                       const _Float16* __restrict__ vt,
                                                       __hip_bfloat16* __restrict__ attn) {
    __shared__ __align__(16) __hip_bfloat16 Ks[2][2][64 * 128];   // [group][buf] 64KB
    __shared__ __align__(16) _Float16 Vts[2][2][128 * 64];        // [group][buf] 64KB
    int tid  = threadIdx.x;
    int lane = tid & 63;
    int wave = tid >> 6;
    int grp  = wave >> 2;
    int wl   = wave & 3;
    int quad = lane >> 4;
    int l15  = lane & 15;
    int pairi = blockIdx.x;
    int bh = blockIdx.y;
    int b  = bh >> 4;
    int h  = bh & 15;
    size_t row0 = (size_t)b * SEQ;
    const _Float16* vbase = vt + (size_t)bh * HD * SEQ;
    const float scale = 0.08838834764831845f;
    const float NEG = -1e30f;

    auto stage = [&](int buf, int kt) {
#pragma unroll
        for (int c = 0; c < 4; c++) {
            int br = (wl * 4 + c) * 4;
            int r  = br + (lane >> 4);
            int cc = (lane & 15) ^ (r & 15);
            gload16(qkv + (row0 + kt * 64 + r) * (size_t)QKVN + DIM + h * HD + cc * 8,
                    &Ks[grp][buf][br * 128]);
        }
#pragma unroll
        for (int c = 0; c < 4; c++) {
            int br = (wl * 4 + c) * 8;
            int r  = br + (lane >> 3);
            int cc = (lane & 7) ^ ((r >> 1) & 7);
            gload16(vbase + (size_t)r * SEQ + kt * 64 + cc * 8, &Vts[grp][buf][br * 64]);
        }
    };

    for (int seg = 0; seg < 2; seg++) {
        int qt = seg ? (15 - pairi) : pairi;
        int half = qt + 1;
        int kbase = grp ? half : 0;

        short8 qf[2][4];
#pragma unroll
        for (int mt = 0; mt < 2; mt++) {
            int qrow = qt * 128 + wl * 32 + mt * 16 + l15;
            const __hip_bfloat16* qptr = qkv + (row0 + qrow) * (size_t)QKVN + h * HD + quad * 8;
#pragma unroll
            for (int c = 0; c < 4; c++) qf[mt][c] = *(const short8*)(qptr + c * 32);
        }
        f32x4 o[2][8] = {};
        float m_[2] = {NEG, NEG}, l_[2] = {0.f, 0.f};

        stage(0, kbase);

        for (int i = 0; i < half; i++) {
            __syncthreads();
            if (i + 1 < half) stage((i + 1) & 1, kbase + i + 1);
            int kt = kbase + i;
            const __hip_bfloat16* ks = Ks[grp][i & 1];
            const _Float16* vts = Vts[grp][i & 1];

            f32x4 s[2][4] = {};
#pragma unroll
            for (int ktile = 0; ktile < 4; ktile++) {
                int R = ktile * 16 + l15;
#pragma unroll
                for (int c = 0; c < 4; c++) {
                    int phys = (c * 4 + quad) ^ (R & 15);
                    short8 kf = *(const short8*)(ks + R * 128 + phys * 8);
                    s[0][ktile] = __builtin_amdgcn_mfma_f32_16x16x32_bf16(kf, qf[0][c], s[0][ktile], 0, 0, 0);
                    s[1][ktile] = __builtin_amdgcn_mfma_f32_16x16x32_bf16(kf, qf[1][c], s[1][ktile], 0, 0, 0);
                }
            }
            bool diag = (kt >= 2 * qt);
            float alpha[2];
#pragma unroll
            for (int mt = 0; mt < 2; mt++) {
                int q = qt * 128 + wl * 32 + mt * 16 + l15;
#pragma unroll
                for (int ktile = 0; ktile < 4; ktile++)
#pragma unroll
                    for (int r = 0; r < 4; r++) {
                        float v = s[mt][ktile][r] * scale;
                        if (diag) {
                            int key = kt * 64 + ktile * 16 + quad * 4 + r;
                            if (key > q) v = NEG;
                        }
                        s[mt][ktile][r] = v;
                    }
                float v = s[mt][0][0];
#pragma unroll
                for (int ktile = 0; ktile < 4; ktile++)
#pragma unroll
                    for (int r = 0; r < 4; r++) v = fmaxf(v, s[mt][ktile][r]);
                v = fmaxf(v, __shfl_xor(v, 16));
                v = fmaxf(v, __shfl_xor(v, 32));
                float mnew = fmaxf(m_[mt], v);
                alpha[mt] = __expf(m_[mt] - mnew);
                m_[mt] = mnew;
                float sum = 0.f;
#pragma unroll
                for (int ktile = 0; ktile < 4; ktile++)
#pragma unroll
                    for (int r = 0; r < 4; r++) {
                        float p = __expf(s[mt][ktile][r] - mnew);
                        s[mt][ktile][r] = p;
                        sum += p;
                    }
                sum += __shfl_xor(sum, 16);
                sum += __shfl_xor(sum, 32);
                l_[mt] = l_[mt] * alpha[mt] + sum;
#pragma unroll
                for (int dt = 0; dt < 8; dt++) o[mt][dt] *= alpha[mt];
            }
            half4 pk[2][4];
#pragma unroll
            for (int mt = 0; mt < 2; mt++)
#pragma unroll
                for (int kc = 0; kc < 4; kc++)
#pragma unroll
                    for (int r = 0; r < 4; r++) pk[mt][kc][r] = (_Float16)s[mt][kc][r];
#pragma unroll
            for (int kc = 0; kc < 4; kc++)
#pragma unroll
                for (int dt = 0; dt < 8; dt++) {
                    int d = dt * 16 + l15;
                    int c4 = ((kc * 4 + quad) ^ (d & 14));
                    half4 vf = *(const half4*)(vts + d * 64 + c4 * 4);
                    o[0][dt] = __builtin_amdgcn_mfma_f32_16x16x16f16(vf, pk[0][kc], o[0][dt], 0, 0, 0);
                    o[1][dt] = __builtin_amdgcn_mfma_f32_16x16x16f16(vf, pk[1][kc], o[1][dt], 0, 0, 0);
                }
        }

        __syncthreads();
        float* o1mb = (float*)&Ks[0][0][0];
        float* mlmb = (float*)&Vts[0][0][0];
        __hip_bfloat16* tb = (__hip_bfloat16*)((char*)&Vts[0][0][0] + 8192);
        if (grp == 1) {
            float* dst = o1mb + wl * 4096;
#pragma unroll
            for (int mt = 0; mt < 2; mt++)
#pragma unroll
                for (int dt = 0; dt < 8; dt++)
#pragma unroll
                    for (int r = 0; r < 4; r++)
                        dst[((mt * 8 + dt) * 4 + r) * 64 + lane] = o[mt][dt][r];
            float* ml = mlmb + (wl * 64 + lane) * 4;
            ml[0] = m_[0]; ml[1] = m_[1]; ml[2] = l_[0]; ml[3] = l_[1];
        }
        __syncthreads();
        if (grp == 0) {
            const float* src = o1mb + wl * 4096;
            const float* ml = mlmb + (wl * 64 + lane) * 4;
#pragma unroll
            for (int mt = 0; mt < 2; mt++) {
                float m1 = ml[mt], l1 = ml[2 + mt];
                float mm = fmaxf(m_[mt], m1);
                float a0 = __expf(m_[mt] - mm), a1 = __expf(m1 - mm);
                float linv = 1.0f / (l_[mt] * a0 + l1 * a1);
#pragma unroll
                for (int dt = 0; dt < 8; dt++)
#pragma unroll
                    for (int r = 0; r < 4; r++)
                        o[mt][dt][r] = (o[mt][dt][r] * a0 +
                                        src[((mt * 8 + dt) * 4 + r) * 64 + lane] * a1) * linv;
            }
            __hip_bfloat16* tw = tb + wl * 4096;
#pragma unroll
            for (int mt = 0; mt < 2; mt++)
#pragma unroll
                for (int dt = 0; dt < 8; dt++) {
                    int q32 = mt * 16 + l15;
                    int c4 = dt * 4 + quad;
                    int phys = c4 ^ ((q32 & 7) << 2);
                    union { unsigned short u[4]; uint2 dw; } pkb;
#pragma unroll
                    for (int r = 0; r < 4; r++) pkb.u[r] = f2bf(o[mt][dt][r]);
                    *(uint2*)(tw + q32 * 128 + phys * 4) = pkb.dw;
                }
#pragma unroll
            for (int pass = 0; pass < 8; pass++) {
                int q32 = pass * 4 + (lane >> 4);
                int p = l15;
                int phys = (p * 2) ^ ((q32 & 7) << 2);
                u32x4 val = *(const u32x4*)(tw + q32 * 128 + phys * 4);
                int qg = qt * 128 + wl * 32 + q32;
                *(u32x4*)(attn + (row0 + qg) * (size_t)DIM + h * HD + p * 8) = val;
            }
        }
        __syncthreads();
    }
}

extern "C" void kernel_launch(void* const* d_in, const int* in_sizes, int n_in,
                              void* d_out, int out_size, void* d_ws, size_t ws_size,
                              hipStream_t stream) {
    const float* x  = (const float*)d_in[0];
    const float* wq = (const float*)d_in[2];
    const float* wk = (const float*)d_in[3];
    const float* wv = (const float*)d_in[4];
    const float* wo = (const float*)d_in[5];
    float* out = (float*)d_out;

    char* ws = (char*)d_ws;
    __hip_bfloat16* xb    = (__hip_bfloat16*)(ws);                 // 4096x2048 (16MB)
    __hip_bfloat16* attn  = (__hip_bfloat16*)(ws);                 // reuses xb after QKV GEMM
    __hip_bfloat16* wqkvb = (__hip_bfloat16*)(ws + 16777216ull);   // 6144x2048 (24MB)
    __hip_bfloat16* wob   = (__hip_bfloat16*)(ws + 41943040ull);   // 2048x2048 (8MB)
    __hip_bfloat16* qkv   = (__hip_bfloat16*)(ws + 50331648ull);   // 4096x6144 (48MB; V cols unused)
    _Float16*       vtg   = (_Float16*)(ws + 100663296ull);        // 32x128x2048 f16 (16MB)

    const int nv = (BATCH * SEQ * DIM + 4 * DIM * DIM) / 4;
    cast_all<<<nv / 256, 256, 0, stream>>>(x, wq, wk, wv, wo, xb, wqkvb, wob);

    // QKV = xb @ wqkvb^T with fused RoPE (Q,K) + V-transpose epilogue
    gemm_bt<1, __hip_bfloat16><<<dim3(QKVN / 128, (BATCH * SEQ) / 128), 256, 0, stream>>>(
        xb, wqkvb, qkv, vtg, BATCH * SEQ, QKVN, DIM);

    flash_kernel<<<dim3(8, BATCH * NH), 512, 0, stream>>>(qkv, vtg, attn);

    // out = attn @ wo^T : M=4096, N=2048, K=2048 (fp32 out)
    gemm_bt<0, float><<<dim3(DIM / 128, (BATCH * SEQ) / 128), 256, 0, stream>>>(
        attn, wob, out, nullptr, BATCH * SEQ, DIM, DIM);
}